// Round 9
// baseline (26.441 us; speedup 1.0000x reference)
//
#include <hip/hip_runtime.h>
#include <math.h>

// SelfRouting2d — collapsed math:
//   softmax over K of K-identical logits == 1/K exactly -> W2, b2 cancel.
//   out[b,k,u] = (1/S[b]) * sum_i W1[k,u,i] * z[b,i]
//   z[b,i] = sum_n a[b,n]*x[b,i,n],  a[b,n]=||x[b,:,n]||_2,  S[b]=sum_n a[b,n]
//
// R9: single kernel node + 256B memset node. Part A = R8's pass1 (proven).
// Cross-block handoff WITHOUT fences (R5's 50-90us came from __threadfence /
// ACQ_REL -> buffer_wbl2 per block):
//   - z/s partials published with RELAXED AGENT atomic stores (sc1 -> coherent
//     point). __syncthreads() drains vmcnt per wave before s_barrier, so after
//     the barrier all stores are globally visible.
//   - arrival via RELAXED AGENT fetch_add (no cache maintenance emitted).
//   - 16th arriver per b finalizes (RELAXED AGENT loads, fixed sum order ->
//     bit-deterministic output). No spinning anywhere.

#define BB 64
#define IN_UNITS 64
#define NCAPS 2048
#define OUT_PER_B 512   // K=32 * U=16
#define CHUNKS 16
#define TILE_N 128

__global__ __launch_bounds__(512) void sr_fused(
    const float* __restrict__ x, const float* __restrict__ W1,
    float* __restrict__ out, float* __restrict__ z_part,
    float* __restrict__ s_part, unsigned int* __restrict__ cnt)
{
  __shared__ __align__(16) float xt[IN_UNITS][TILE_N];  // 32KB, quad-swizzled
  __shared__ float4 ssqp[8][32];                        // 4KB
  __shared__ __align__(16) float a_lds[TILE_N];         // 512B
  __shared__ float ztmp[8][IN_UNITS];                   // 2KB
  __shared__ float swave[2];
  __shared__ __align__(16) float z_l[IN_UNITS];         // 256B
  __shared__ float sinv_l;
  __shared__ int islast;

  const int bid   = blockIdx.x;
  const int b     = bid >> 4;          // CHUNKS = 16
  const int chunk = bid & 15;
  const int n0    = chunk * TILE_N;
  const int t     = threadIdx.x;

  const int q = t & 31;                // quad (4 n's) of the 128-float row chunk
  const int g = t >> 5;                // 0..15 -> owns rows g*4 .. g*4+3

  // ---- part A phase 1: coalesced float4 read (1KB/wave-instr) + ssq on the
  // fly; stage tile to LDS with XOR quad swizzle (conflict-minimal b128).
  const float* xb = x + (size_t)b * IN_UNITS * NCAPS + n0;
  float4 ssq4 = make_float4(0.f, 0.f, 0.f, 0.f);
  #pragma unroll
  for (int j = 0; j < 4; ++j) {
    const int r = g * 4 + j;
    float4 xv = reinterpret_cast<const float4*>(xb + (size_t)r * NCAPS)[q];
    ssq4.x = fmaf(xv.x, xv.x, ssq4.x);
    ssq4.y = fmaf(xv.y, xv.y, ssq4.y);
    ssq4.z = fmaf(xv.z, xv.z, ssq4.z);
    ssq4.w = fmaf(xv.w, xv.w, ssq4.w);
    reinterpret_cast<float4*>(&xt[r][0])[q ^ (r & 7)] = xv;  // XOR swizzle
  }
  // pair-reduce g with g^1 (lanes t, t^32 share a wave) -> 8 partial rows
  ssq4.x += __shfl_xor(ssq4.x, 32, 64);
  ssq4.y += __shfl_xor(ssq4.y, 32, 64);
  ssq4.z += __shfl_xor(ssq4.z, 32, 64);
  ssq4.w += __shfl_xor(ssq4.w, 32, 64);
  if ((g & 1) == 0) ssqp[g >> 1][q] = ssq4;
  __syncthreads();

  // ---- a[n] = sqrt(sum of 8 partials); threads 0..127 (waves 0,1) own one n
  if (t < TILE_N) {
    const int nq = t >> 2, c = t & 3;
    float ss = 0.f;
    #pragma unroll
    for (int k = 0; k < 8; ++k) {
      const int kk = (k + (t & 7)) & 7;  // rotate -> bank t%32
      ss += reinterpret_cast<const float*>(&ssqp[kk][nq])[c];
    }
    float a = sqrtf(ss);
    a_lds[t] = a;
    float s = a;
    #pragma unroll
    for (int off = 32; off > 0; off >>= 1) s += __shfl_down(s, off, 64);
    if ((t & 63) == 0) swave[t >> 6] = s;
  }
  __syncthreads();
  if (t == 0)
    __hip_atomic_store(&s_part[b * CHUNKS + chunk], swave[0] + swave[1],
                       __ATOMIC_RELAXED, __HIP_MEMORY_SCOPE_AGENT);

  // ---- part A phase 2: z partial from LDS (conflict-minimal b128 pattern)
  {
    const int i  = t & 63;
    const int tg = t >> 6;             // 0..7 -> owns quads tg*4 .. tg*4+3
    const float4* a4 = reinterpret_cast<const float4*>(a_lds);
    float acc = 0.f;
    #pragma unroll
    for (int m = 0; m < 4; ++m) {
      const int qq = tg * 4 + m;
      float4 xv = reinterpret_cast<const float4*>(&xt[i][0])[qq ^ (i & 7)];
      float4 av = a4[qq];              // wave-uniform -> broadcast
      acc = fmaf(xv.x, av.x, acc);
      acc = fmaf(xv.y, av.y, acc);
      acc = fmaf(xv.z, av.z, acc);
      acc = fmaf(xv.w, av.w, acc);
    }
    ztmp[tg][i] = acc;
  }
  __syncthreads();
  if (t < IN_UNITS) {
    float zz = 0.f;
    #pragma unroll
    for (int k = 0; k < 8; ++k) zz += ztmp[k][t];
    __hip_atomic_store(&z_part[((size_t)b * CHUNKS + chunk) * IN_UNITS + t], zz,
                       __ATOMIC_RELAXED, __HIP_MEMORY_SCOPE_AGENT);
  }

  // ---- arrival. The barrier drains every wave's stores (compiler emits
  // s_waitcnt vmcnt(0) before s_barrier), so all agent stores are visible
  // at the coherent point before any fetch_add. RELAXED -> no wbL2.
  __syncthreads();
  if (t == 0) {
    unsigned int old = __hip_atomic_fetch_add(&cnt[b], 1u, __ATOMIC_RELAXED,
                                              __HIP_MEMORY_SCOPE_AGENT);
    islast = (old == CHUNKS - 1) ? 1 : 0;
  }
  __syncthreads();
  if (!islast) return;

  // ---- finalize b (16th arriver only): gather partials with agent loads
  {
    const int i = t & 63, tg = t >> 6;   // 8 groups x 2 chunks each
    float zz = 0.f;
    #pragma unroll
    for (int k = 0; k < 2; ++k)
      zz += __hip_atomic_load(
          &z_part[((size_t)b * CHUNKS + tg * 2 + k) * IN_UNITS + i],
          __ATOMIC_RELAXED, __HIP_MEMORY_SCOPE_AGENT);
    ztmp[tg][i] = zz;
  }
  if (t == 0) {
    float ss = 0.f;
    #pragma unroll
    for (int c = 0; c < CHUNKS; ++c)
      ss += __hip_atomic_load(&s_part[b * CHUNKS + c],
                              __ATOMIC_RELAXED, __HIP_MEMORY_SCOPE_AGENT);
    sinv_l = 1.0f / ss;
  }
  __syncthreads();
  if (t < IN_UNITS) {
    float zz = 0.f;
    #pragma unroll
    for (int k = 0; k < 8; ++k) zz += ztmp[k][t];
    z_l[t] = zz;
  }
  __syncthreads();

  // 512 outputs: 4 threads/output, 4 passes; W1 reads contiguous 64B lane
  // stride (wave covers 4KB of W1 per pass, fully coalesced).
  const int part = t & 3;
  const int jl   = t >> 2;             // 0..127
  const float4* z4 = reinterpret_cast<const float4*>(z_l) + part * 4;
  const float4 zv0 = z4[0], zv1 = z4[1], zv2 = z4[2], zv3 = z4[3];
  const float si = sinv_l;
  #pragma unroll
  for (int p = 0; p < 4; ++p) {
    const int j = p * 128 + jl;
    const float4* w4 = reinterpret_cast<const float4*>(
        W1 + (size_t)j * IN_UNITS + part * 16);
    float4 wv0 = w4[0], wv1 = w4[1], wv2 = w4[2], wv3 = w4[3];
    float acc = 0.f;
    acc = fmaf(wv0.x, zv0.x, acc); acc = fmaf(wv0.y, zv0.y, acc);
    acc = fmaf(wv0.z, zv0.z, acc); acc = fmaf(wv0.w, zv0.w, acc);
    acc = fmaf(wv1.x, zv1.x, acc); acc = fmaf(wv1.y, zv1.y, acc);
    acc = fmaf(wv1.z, zv1.z, acc); acc = fmaf(wv1.w, zv1.w, acc);
    acc = fmaf(wv2.x, zv2.x, acc); acc = fmaf(wv2.y, zv2.y, acc);
    acc = fmaf(wv2.z, zv2.z, acc); acc = fmaf(wv2.w, zv2.w, acc);
    acc = fmaf(wv3.x, zv3.x, acc); acc = fmaf(wv3.y, zv3.y, acc);
    acc = fmaf(wv3.z, zv3.z, acc); acc = fmaf(wv3.w, zv3.w, acc);
    acc += __shfl_xor(acc, 1);
    acc += __shfl_xor(acc, 2);
    if (part == 0) out[(size_t)b * OUT_PER_B + j] = acc * si;
  }
}

extern "C" void kernel_launch(void* const* d_in, const int* in_sizes, int n_in,
                              void* d_out, int out_size, void* d_ws, size_t ws_size,
                              hipStream_t stream) {
  const float* x  = (const float*)d_in[0];
  const float* W1 = (const float*)d_in[1];
  // d_in[2] (W2) and d_in[3] (b2) cancel exactly: softmax over the K axis of
  // K-identical logits is uniform 1/K regardless of logit values.
  float* out = (float*)d_out;

  float* z_part = (float*)d_ws;                               // 64*16*64 f32
  float* s_part = z_part + (size_t)BB * CHUNKS * IN_UNITS;    // 64*16 f32
  unsigned int* cnt = (unsigned int*)(s_part + BB * CHUNKS);  // 64 u32

  hipMemsetAsync(cnt, 0, BB * sizeof(unsigned int), stream);  // 256B graph node
  sr_fused<<<dim3(BB * CHUNKS), dim3(512), 0, stream>>>(x, W1, out,
                                                        z_part, s_part, cnt);
}

// Round 10
// 13.376 us; speedup vs baseline: 1.9767x; 1.9767x over previous
//
#include <hip/hip_runtime.h>
#include <math.h>

// SelfRouting2d — collapsed math:
//   softmax over K of K-identical logits == 1/K exactly -> W2, b2 cancel.
//   out[b,k,u] = (1/S[b]) * sum_i W1[k,u,i] * z[b,i]
//   z[b,i] = sum_n a[b,n]*x[b,i,n],  a[b,n]=||x[b,:,n]||_2,  S[b]=sum_n a[b,n]
//
// R10 = R8 restored (measured best: 13.25us). Two kernels — the kernel
// boundary is the ONLY cheap cross-block barrier on gfx950: all three fusion
// mechanisms measured 2x worse (R4 grid.sync 89us; R5 fences/buffer_wbl2
// 90us; R9 relaxed agent atomics 26us).
// Pass1: 1024 blocks x 512 thr, TILE_N=128, LDS 38.6KB -> 4 blocks/CU
// x 8 waves = 32 waves/CU (hw max); x read once, coalesced float4.

#define BB 64
#define IN_UNITS 64
#define NCAPS 2048
#define OUT_PER_B 512   // K=32 * U=16
#define CHUNKS 16
#define TILE_N 128

__global__ __launch_bounds__(512) void sr_pass1(
    const float* __restrict__ x, float* __restrict__ z_part, float* __restrict__ s_part)
{
  __shared__ __align__(16) float xt[IN_UNITS][TILE_N];  // 32KB, quad-swizzled
  __shared__ float4 ssqp[8][32];                        // 4KB (g-pair, q) partials
  __shared__ __align__(16) float a_lds[TILE_N];         // 512B
  __shared__ float ztmp[8][IN_UNITS];                   // 2KB
  __shared__ float swave[2];
  // total ~38.6KB -> 4 blocks/CU at 512 thr = 32 waves/CU (max)

  const int bid   = blockIdx.x;
  const int b     = bid >> 4;          // CHUNKS = 16
  const int chunk = bid & 15;
  const int n0    = chunk * TILE_N;
  const int t     = threadIdx.x;

  const int q = t & 31;                // quad (4 n's) of the 128-float row chunk
  const int g = t >> 5;                // 0..15 -> owns rows g*4 .. g*4+3

  // ---- phase 1: coalesced float4 read (1KB/wave-instr) + ssq on the fly;
  // stage tile to LDS with XOR quad swizzle (write: 2 rows/wave, 32 perm'd
  // quads each -> every bank x8, the b128 structural minimum).
  const float* xb = x + (size_t)b * IN_UNITS * NCAPS + n0;
  float4 ssq4 = make_float4(0.f, 0.f, 0.f, 0.f);
  #pragma unroll
  for (int j = 0; j < 4; ++j) {
    const int r = g * 4 + j;
    float4 xv = reinterpret_cast<const float4*>(xb + (size_t)r * NCAPS)[q];
    ssq4.x = fmaf(xv.x, xv.x, ssq4.x);
    ssq4.y = fmaf(xv.y, xv.y, ssq4.y);
    ssq4.z = fmaf(xv.z, xv.z, ssq4.z);
    ssq4.w = fmaf(xv.w, xv.w, ssq4.w);
    reinterpret_cast<float4*>(&xt[r][0])[q ^ (r & 7)] = xv;  // XOR swizzle
  }
  // pair-reduce g with g^1 (lanes t, t^32 share a wave) -> 8 partial rows
  ssq4.x += __shfl_xor(ssq4.x, 32, 64);
  ssq4.y += __shfl_xor(ssq4.y, 32, 64);
  ssq4.z += __shfl_xor(ssq4.z, 32, 64);
  ssq4.w += __shfl_xor(ssq4.w, 32, 64);
  if ((g & 1) == 0) ssqp[g >> 1][q] = ssq4;   // 8 partials (8 rows each)
  __syncthreads();

  // ---- a[n] = sqrt(sum of 8 partials); threads 0..127 (waves 0,1) own one n.
  // rotated k-index -> dword idx kk*128 + t -> bank t%32 (2 lanes/bank, free)
  if (t < TILE_N) {
    const int nq = t >> 2, c = t & 3;
    float ss = 0.f;
    #pragma unroll
    for (int k = 0; k < 8; ++k) {
      const int kk = (k + (t & 7)) & 7;
      ss += reinterpret_cast<const float*>(&ssqp[kk][nq])[c];
    }
    float a = sqrtf(ss);
    a_lds[t] = a;
    float s = a;
    #pragma unroll
    for (int off = 32; off > 0; off >>= 1) s += __shfl_down(s, off, 64);
    if ((t & 63) == 0) swave[t >> 6] = s;
  }
  __syncthreads();
  if (t == 0) s_part[b * CHUNKS + chunk] = swave[0] + swave[1];

  // ---- phase 2: z partial from LDS. Per wave tg is constant; read quad
  // p=qq^(i&7) is the conflict-minimal b128 pattern (2 addrs/bank per
  // 16-lane phase). a4[qq] is wave-uniform -> broadcast.
  {
    const int i  = t & 63;
    const int tg = t >> 6;             // 0..7 -> owns quads tg*4 .. tg*4+3
    const float4* a4 = reinterpret_cast<const float4*>(a_lds);
    float acc = 0.f;
    #pragma unroll
    for (int m = 0; m < 4; ++m) {
      const int qq = tg * 4 + m;
      float4 xv = reinterpret_cast<const float4*>(&xt[i][0])[qq ^ (i & 7)];
      float4 av = a4[qq];
      acc = fmaf(xv.x, av.x, acc);
      acc = fmaf(xv.y, av.y, acc);
      acc = fmaf(xv.z, av.z, acc);
      acc = fmaf(xv.w, av.w, acc);
    }
    ztmp[tg][i] = acc;
  }
  __syncthreads();
  if (t < IN_UNITS) {
    float zz = 0.f;
    #pragma unroll
    for (int k = 0; k < 8; ++k) zz += ztmp[k][t];
    z_part[((size_t)b * CHUNKS + chunk) * IN_UNITS + t] = zz;
  }
}

__global__ __launch_bounds__(256) void sr_pass2(
    const float* __restrict__ z_part, const float* __restrict__ s_part,
    const float* __restrict__ W1, float* __restrict__ out)
{
  __shared__ float ztmp[4][IN_UNITS];
  __shared__ __align__(16) float z_l[IN_UNITS];
  const int bid = blockIdx.x;
  const int b   = bid >> 3;            // 8 j-groups per b
  const int g   = bid & 7;
  const int t   = threadIdx.x;

  // coalesced z gather: lanes span i; thread-group tg sums 4 of the 16 chunks
  {
    const int i = t & 63, tg = t >> 6;
    float zz = 0.f;
    #pragma unroll
    for (int k = 0; k < 4; ++k)
      zz += z_part[((size_t)b * CHUNKS + tg * 4 + k) * IN_UNITS + i];
    ztmp[tg][i] = zz;
  }
  float ss = 0.f;
  #pragma unroll
  for (int c = 0; c < CHUNKS; ++c) ss += s_part[b * CHUNKS + c];  // uniform -> scalar
  const float sinv = 1.0f / ss;
  __syncthreads();
  if (t < IN_UNITS) z_l[t] = ztmp[0][t] + ztmp[1][t] + ztmp[2][t] + ztmp[3][t];
  __syncthreads();

  // output j = g*64 + (t>>2); 4 threads/output -> W1 reads contiguous 64B
  // lane stride (wave covers 4KB of W1 per pass, fully coalesced).
  const int jl   = t >> 2;
  const int part = t & 3;
  const int j    = g * 64 + jl;
  const float4* w4 = reinterpret_cast<const float4*>(W1 + (size_t)j * IN_UNITS + part * 16);
  const float4* z4 = reinterpret_cast<const float4*>(z_l) + part * 4;
  float acc = 0.f;
  #pragma unroll
  for (int jj = 0; jj < 4; ++jj) {
    float4 wv = w4[jj];
    float4 zv = z4[jj];
    acc = fmaf(wv.x, zv.x, acc);
    acc = fmaf(wv.y, zv.y, acc);
    acc = fmaf(wv.z, zv.z, acc);
    acc = fmaf(wv.w, zv.w, acc);
  }
  acc += __shfl_xor(acc, 1);
  acc += __shfl_xor(acc, 2);
  if (part == 0) out[(size_t)b * OUT_PER_B + j] = acc * sinv;
}

extern "C" void kernel_launch(void* const* d_in, const int* in_sizes, int n_in,
                              void* d_out, int out_size, void* d_ws, size_t ws_size,
                              hipStream_t stream) {
  const float* x  = (const float*)d_in[0];
  const float* W1 = (const float*)d_in[1];
  // d_in[2] (W2) and d_in[3] (b2) cancel exactly: softmax over the K axis of
  // K-identical logits is uniform 1/K regardless of logit values.
  float* out = (float*)d_out;

  float* z_part = (float*)d_ws;                               // 64*16*64 f32
  float* s_part = z_part + (size_t)BB * CHUNKS * IN_UNITS;    // 64*16 f32

  sr_pass1<<<dim3(BB * CHUNKS), dim3(512), 0, stream>>>(x, z_part, s_part);
  sr_pass2<<<dim3(BB * 8), dim3(256), 0, stream>>>(z_part, s_part, W1, out);
}